// Round 7
// baseline (350.446 us; speedup 1.0000x reference)
//
#include <hip/hip_runtime.h>
#include <hip/hip_fp16.h>
#include <math.h>

#define NN 100000
#define NE 1600000
#define NBUK 391        // ceil(NN/256) buckets of 256 dst nodes
#define CAP 4608        // per-bucket region capacity (avg 4096, +8 sigma)
#define EPB 4096        // edges per phase-B block

__device__ __forceinline__ float leaky02(float v) {
    return v > 0.0f ? v : 0.2f * v;
}

// ---------------- CSR build via LDS radix (no device-random atomics) --------

__global__ __launch_bounds__(256) void k_bucket(
    const int* __restrict__ src, const int* __restrict__ dst,
    int* __restrict__ bucketCnt, int* __restrict__ gBuf)
{
    __shared__ int stg[EPB];
    __shared__ int tgt[EPB];
    __shared__ int lcnt[NBUK];
    __shared__ int lexc[NBUK];
    __shared__ int lgb[NBUK];
    __shared__ int totalLocal;
    const int t = threadIdx.x;
    const int e0 = blockIdx.x * EPB;

    for (int i = t; i < NBUK; i += 256) lcnt[i] = 0;
    __syncthreads();

    int bk[16], pk[16];
    #pragma unroll
    for (int j = 0; j < 16; ++j) {
        const int e = e0 + j * 256 + t;
        if (e < NE) {
            const int d = dst[e];
            bk[j] = d >> 8;
            pk[j] = (src[e] << 8) | (d & 255);
            atomicAdd(&lcnt[bk[j]], 1);
        } else bk[j] = -1;
    }
    __syncthreads();

    if (t < 64) {
        int carry = 0;
        for (int c = 0; c < NBUK; c += 64) {
            const int idx = c + t;
            int v = (idx < NBUK) ? lcnt[idx] : 0;
            int inc = v;
            #pragma unroll
            for (int off = 1; off < 64; off <<= 1) {
                int u = __shfl_up(inc, off, 64);
                if (t >= off) inc += u;
            }
            if (idx < NBUK) lexc[idx] = carry + inc - v;
            carry += __shfl(inc, 63, 64);
        }
        if (t == 0) totalLocal = carry;
    }
    __syncthreads();

    for (int i = t; i < NBUK; i += 256) {
        const int c = lcnt[i];
        lgb[i] = c ? atomicAdd(&bucketCnt[i], c) : 0;
        lcnt[i] = 0;
    }
    __syncthreads();

    #pragma unroll
    for (int j = 0; j < 16; ++j) {
        if (bk[j] >= 0) {
            const int r = atomicAdd(&lcnt[bk[j]], 1);
            const int p = lexc[bk[j]] + r;
            stg[p] = pk[j];
            int slot = lgb[bk[j]] + r;
            if (slot >= CAP) slot = CAP - 1;   // statistically impossible
            tgt[p] = bk[j] * CAP + slot;
        }
    }
    __syncthreads();

    const int tot = totalLocal;
    for (int i = t; i < tot; i += 256)
        gBuf[tgt[i]] = stg[i];
}

__global__ __launch_bounds__(64) void k_bbase(
    const int* __restrict__ bucketCnt, int* __restrict__ bucketBase,
    int* __restrict__ row_ptr)
{
    const int t = threadIdx.x;
    int carry = 0;
    for (int c = 0; c < NBUK; c += 64) {
        const int idx = c + t;
        int v = (idx < NBUK) ? bucketCnt[idx] : 0;
        int inc = v;
        #pragma unroll
        for (int off = 1; off < 64; off <<= 1) {
            int u = __shfl_up(inc, off, 64);
            if (t >= off) inc += u;
        }
        if (idx < NBUK) bucketBase[idx] = carry + inc - v;
        carry += __shfl(inc, 63, 64);
    }
    if (t == 0) row_ptr[NN] = NE;
}

__global__ __launch_bounds__(256) void k_csr_local(
    const int* __restrict__ bucketCnt, const int* __restrict__ bucketBase,
    const int* __restrict__ gBuf,
    int* __restrict__ row_ptr, int* __restrict__ ssrc)
{
    __shared__ int stg2[CAP];
    __shared__ int stg3[CAP];
    __shared__ int c2[256];
    __shared__ int sc[256];
    const int t = threadIdx.x;
    const int k = blockIdx.x;
    const int cnt = min(bucketCnt[k], CAP);
    const int gb  = bucketBase[k];

    c2[t] = 0;
    __syncthreads();
    for (int i = t; i < cnt; i += 256) {
        const int pk = gBuf[k * CAP + i];
        stg2[i] = pk;
        atomicAdd(&c2[pk & 255], 1);
    }
    __syncthreads();
    if (t < 64) {
        int carry = 0;
        for (int c = 0; c < 256; c += 64) {
            int v = c2[c + t];
            int inc = v;
            #pragma unroll
            for (int off = 1; off < 64; off <<= 1) {
                int u = __shfl_up(inc, off, 64);
                if (t >= off) inc += u;
            }
            sc[c + t] = carry + inc - v;
            carry += __shfl(inc, 63, 64);
        }
    }
    __syncthreads();
    const int node = (k << 8) + t;
    if (node < NN) row_ptr[node] = gb + sc[t];
    c2[t] = 0;
    __syncthreads();
    for (int i = t; i < cnt; i += 256) {
        const int pk = stg2[i];
        const int dl = pk & 255;
        const int r = atomicAdd(&c2[dl], 1);
        stg3[sc[dl] + r] = pk >> 8;
    }
    __syncthreads();
    for (int i = t; i < cnt; i += 256)
        ssrc[gb + i] = stg3[i];
}

// ---------------- Layer kernels (H=4, D=16, F=64) ----------------

// GEMM z = x@W (fp16 out) + attention coeffs. W column in 64 VGPRs per lane;
// x staged in LDS, read as float4 same-address broadcasts (conflict-free).
// 64 nodes/block (16/wave, 4 in flight), grid = ceil(NN/64) = 1563.
__global__ __launch_bounds__(256) void k_node_prep(
    const float* __restrict__ xin, const float* __restrict__ W,
    const float* __restrict__ al, const float* __restrict__ ar,
    __half* __restrict__ z, float* __restrict__ el, float* __restrict__ er)
{
    __shared__ __align__(16) float xs[64][64];
    const int t = threadIdx.x;
    const int lane = t & 63, wv = t >> 6;
    const int nodeBase = blockIdx.x * 64;

    // stage x: 64 nodes x 64 floats = 1024 float4s, 4 per thread
    {
        const float4* xin4 = (const float4*)(xin + (size_t)nodeBase * 64);
        float4* xs4 = (float4*)&xs[0][0];
        const int lim4 = NN * 16 - nodeBase * 16;   // valid float4s from base
        #pragma unroll
        for (int i = 0; i < 4; ++i) {
            const int idx = t + 256 * i;
            if (idx < lim4) xs4[idx] = xin4[idx];
        }
    }

    // W column `lane` into registers (coalesced, L2-hot)
    float wc[64];
    #pragma unroll
    for (int k = 0; k < 64; ++k) wc[k] = W[k * 64 + lane];
    const float a_l = al[lane], a_r = ar[lane];
    __syncthreads();

    #pragma unroll 1
    for (int g = 0; g < 4; ++g) {
        const int n0 = wv * 16 + g * 4;   // local node index of first of 4
        float acc0 = 0.f, acc1 = 0.f, acc2 = 0.f, acc3 = 0.f;
        #pragma unroll
        for (int k4 = 0; k4 < 16; ++k4) {
            const float4 x0 = *(const float4*)&xs[n0 + 0][k4 * 4];
            const float4 x1 = *(const float4*)&xs[n0 + 1][k4 * 4];
            const float4 x2 = *(const float4*)&xs[n0 + 2][k4 * 4];
            const float4 x3 = *(const float4*)&xs[n0 + 3][k4 * 4];
            const float w0 = wc[k4 * 4 + 0], w1 = wc[k4 * 4 + 1];
            const float w2 = wc[k4 * 4 + 2], w3 = wc[k4 * 4 + 3];
            acc0 += x0.x * w0 + x0.y * w1 + x0.z * w2 + x0.w * w3;
            acc1 += x1.x * w0 + x1.y * w1 + x1.z * w2 + x1.w * w3;
            acc2 += x2.x * w0 + x2.y * w1 + x2.z * w2 + x2.w * w3;
            acc3 += x3.x * w0 + x3.y * w1 + x3.z * w2 + x3.w * w3;
        }
        #pragma unroll
        for (int i = 0; i < 4; ++i) {
            const float accv = (i == 0) ? acc0 : (i == 1) ? acc1
                             : (i == 2) ? acc2 : acc3;
            const int n = nodeBase + n0 + i;
            if (n < NN) {
                z[(size_t)n * 64 + lane] = __float2half(accv);
                float pl = accv * a_l, pr = accv * a_r;
                #pragma unroll
                for (int off = 8; off > 0; off >>= 1) {
                    pl += __shfl_xor(pl, off, 16);
                    pr += __shfl_xor(pr, off, 16);
                }
                if ((lane & 15) == 0) {
                    const int h = lane >> 4;
                    el[n * 4 + h] = pl;
                    er[n * 4 + h] = pr;
                }
            }
        }
    }
}

// Fused aggregation: 16 lanes per z-row (half4/lane) -> one wave-load fetches
// 4 edges' rows (8 lines in flight). Exp-dedup: lane l computes exp for
// (edge l>>2, head l&3) per 16-edge chunk. No max pass.
__global__ __launch_bounds__(256) void k_csr_agg(
    const int* __restrict__ row_ptr, const int* __restrict__ ssrc,
    const float* __restrict__ el, const float* __restrict__ er,
    const __half* __restrict__ z, const float* __restrict__ b,
    float* __restrict__ xout,       // [NN][64] or nullptr
    const float* __restrict__ Wo,   // [64] (used when xout==nullptr)
    float* __restrict__ zo)         // [NN]  (used when xout==nullptr)
{
    const int t = threadIdx.x;
    const int wv = t >> 6, l = t & 63;
    const int sg = l >> 4, sl = l & 15;
    const int eh = l & 3;             // head this lane evaluates exp for
    const int hh = sl >> 2;           // head of this lane's feature quad
    const int n = blockIdx.x * 4 + wv;
    const int beg = row_ptr[n], deg = row_ptr[n + 1] - beg;
    const float er_eh = er[n * 4 + eh];

    float4 acc = {0.f, 0.f, 0.f, 0.f};
    float den4 = 0.f;
    for (int base = 0; base < deg; base += 16) {
        const int myE = base + (l >> 2);
        int s = 0; float x = 0.f;
        if (myE < deg) {
            s = ssrc[beg + myE];
            x = __expf(leaky02(el[s * 4 + eh] + er_eh));
        }
        den4 += x;
        const int rem = deg - base;
        const int nk = (min(rem, 16) + 3) >> 2;
        for (int k = 0; k < nk; ++k) {
            const int ec = k * 4 + sg;                       // edge in chunk
            const int   sj = __shfl(s, ec * 4, 64);
            const float xj = __shfl(x, ec * 4 + hh, 64);
            const uint2 raw = *(const uint2*)(z + (size_t)sj * 64 + sl * 4);
            const float2 f01 = __half22float2(*(const __half2*)&raw.x);
            const float2 f23 = __half22float2(*(const __half2*)&raw.y);
            acc.x += xj * f01.x; acc.y += xj * f01.y;
            acc.z += xj * f23.x; acc.w += xj * f23.y;
        }
    }
    #pragma unroll
    for (int off = 16; off < 64; off <<= 1) {
        acc.x += __shfl_xor(acc.x, off, 64);
        acc.y += __shfl_xor(acc.y, off, 64);
        acc.z += __shfl_xor(acc.z, off, 64);
        acc.w += __shfl_xor(acc.w, off, 64);
    }
    #pragma unroll
    for (int off = 4; off < 64; off <<= 1) den4 += __shfl_xor(den4, off, 64);
    const float den = fmaxf(__shfl(den4, hh, 64), 1e-9f);

    const float4 b4 = *(const float4*)(b + sl * 4);
    float4 v;
    v.x = fmaxf(acc.x / den + b4.x, 0.f);
    v.y = fmaxf(acc.y / den + b4.y, 0.f);
    v.z = fmaxf(acc.z / den + b4.z, 0.f);
    v.w = fmaxf(acc.w / den + b4.w, 0.f);

    if (xout) {
        if (l < 16) *(float4*)(xout + (size_t)n * 64 + sl * 4) = v;
    } else {
        const float4 w4 = *(const float4*)(Wo + sl * 4);
        float p = v.x * w4.x + v.y * w4.y + v.z * w4.z + v.w * w4.w;
        #pragma unroll
        for (int off = 1; off < 16; off <<= 1) p += __shfl_xor(p, off, 64);
        if (l == 0) zo[n] = p;
    }
}

// ---------------- Output layer (H=1, D=1), single-pass, 16 lanes/node -------

__global__ __launch_bounds__(256) void k_csr_agg_o(
    const int* __restrict__ row_ptr, const int* __restrict__ ssrc,
    const float* __restrict__ zo, const float* __restrict__ alo,
    const float* __restrict__ aro, const float* __restrict__ bo,
    float* __restrict__ out)
{
    const int t = threadIdx.x, l = t & 15;
    const int n = blockIdx.x * 16 + (t >> 4);
    const float a = alo[0];
    const float zr = aro[0] * zo[n];
    const int beg = row_ptr[n], end = row_ptr[n + 1];

    float den = 0.f, accv = 0.f;
    for (int i = beg + l; i < end; i += 16) {
        const float zs = zo[ssrc[i]];
        const float ex = __expf(leaky02(a * zs + zr));
        den += ex; accv += ex * zs;
    }
    #pragma unroll
    for (int off = 8; off; off >>= 1) {
        den  += __shfl_xor(den, off, 16);
        accv += __shfl_xor(accv, off, 16);
    }
    if (l == 0) out[n] = accv / fmaxf(den, 1e-9f) + bo[0];
}

// ---------------- Launch ----------------

extern "C" void kernel_launch(void* const* d_in, const int* in_sizes, int n_in,
                              void* d_out, int out_size, void* d_ws, size_t ws_size,
                              hipStream_t stream) {
    const float* feat = (const float*)d_in[0];
    const int*   src  = (const int*)d_in[1];
    const int*   dst  = (const int*)d_in[2];
    const float* W0   = (const float*)d_in[3];
    const float* al0  = (const float*)d_in[4];
    const float* ar0  = (const float*)d_in[5];
    const float* b0   = (const float*)d_in[6];
    const float* W1   = (const float*)d_in[7];
    const float* al1  = (const float*)d_in[8];
    const float* ar1  = (const float*)d_in[9];
    const float* b1   = (const float*)d_in[10];
    const float* Wo   = (const float*)d_in[11];
    const float* alo  = (const float*)d_in[12];
    const float* aro  = (const float*)d_in[13];
    const float* bo   = (const float*)d_in[14];
    float* out = (float*)d_out;

    // workspace carve-up (int region padded so z/xA are 16B-aligned)
    int* bucketCnt  = (int*)d_ws;                   // [NBUK] (zeroed)
    int* bucketBase = bucketCnt + NBUK;             // [NBUK]
    int* row_ptr    = bucketBase + NBUK;            // [NN+1]
    int* gBuf       = row_ptr + (NN + 2);           // [NBUK*CAP] (+1 pad int)
    int* ssrc       = gBuf + (size_t)NBUK * CAP;    // [NE]
    __half* z  = (__half*)(ssrc + NE);              // [NN*64] fp16, 16B-aligned
    float* xA  = (float*)(z + (size_t)NN * 64);     // [NN*64]
    float* el  = xA + (size_t)NN * 64;              // [NN*4]
    float* er  = el + (size_t)NN * 4;               // [NN*4]
    float* zo  = er + (size_t)NN * 4;               // [NN]

    const int gPrep = (NN + 63) / 64;    // 1563
    const int gN16  = NN / 16;           // 6250
    const int gAgg  = NN / 4;            // 25000

    // CSR build (LDS radix, 3 kernels)
    hipMemsetAsync(bucketCnt, 0, NBUK * sizeof(int), stream);
    k_bucket   <<<NBUK, 256, 0, stream>>>(src, dst, bucketCnt, gBuf);
    k_bbase    <<<1, 64, 0, stream>>>(bucketCnt, bucketBase, row_ptr);
    k_csr_local<<<NBUK, 256, 0, stream>>>(bucketCnt, bucketBase, gBuf,
                                          row_ptr, ssrc);

    // Layer 0: feat -> xA
    k_node_prep<<<gPrep, 256, 0, stream>>>(feat, W0, al0, ar0, z, el, er);
    k_csr_agg  <<<gAgg, 256, 0, stream>>>(row_ptr, ssrc, el, er, z, b0,
                                          xA, nullptr, nullptr);

    // Layer 1: xA -> zo (output-layer GEMV fused into agg epilogue)
    k_node_prep<<<gPrep, 256, 0, stream>>>(xA, W1, al1, ar1, z, el, er);
    k_csr_agg  <<<gAgg, 256, 0, stream>>>(row_ptr, ssrc, el, er, z, b1,
                                          nullptr, Wo, zo);

    // Output layer
    k_csr_agg_o<<<gN16, 256, 0, stream>>>(row_ptr, ssrc, zo, alo, aro, bo, out);
}

// Round 8
// 285.435 us; speedup vs baseline: 1.2278x; 1.2278x over previous
//
#include <hip/hip_runtime.h>
#include <hip/hip_fp16.h>
#include <math.h>

#define NN 100000
#define NE 1600000
#define NBUK 391        // ceil(NN/256) buckets of 256 dst nodes
#define CAP 4608        // per-bucket region capacity (avg 4096, +8 sigma)
#define EPB 4096        // edges per phase-B block

__device__ __forceinline__ float leaky02(float v) {
    return v > 0.0f ? v : 0.2f * v;
}

// ---------------- CSR build via LDS radix (no device-random atomics) --------

__global__ __launch_bounds__(256) void k_bucket(
    const int* __restrict__ src, const int* __restrict__ dst,
    int* __restrict__ bucketCnt, int* __restrict__ gBuf)
{
    __shared__ int stg[EPB];
    __shared__ int tgt[EPB];
    __shared__ int lcnt[NBUK];
    __shared__ int lexc[NBUK];
    __shared__ int lgb[NBUK];
    __shared__ int totalLocal;
    const int t = threadIdx.x;
    const int e0 = blockIdx.x * EPB;

    for (int i = t; i < NBUK; i += 256) lcnt[i] = 0;
    __syncthreads();

    int bk[16], pk[16];
    #pragma unroll
    for (int j = 0; j < 16; ++j) {
        const int e = e0 + j * 256 + t;
        if (e < NE) {
            const int d = dst[e];
            bk[j] = d >> 8;
            pk[j] = (src[e] << 8) | (d & 255);
            atomicAdd(&lcnt[bk[j]], 1);
        } else bk[j] = -1;
    }
    __syncthreads();

    if (t < 64) {
        int carry = 0;
        for (int c = 0; c < NBUK; c += 64) {
            const int idx = c + t;
            int v = (idx < NBUK) ? lcnt[idx] : 0;
            int inc = v;
            #pragma unroll
            for (int off = 1; off < 64; off <<= 1) {
                int u = __shfl_up(inc, off, 64);
                if (t >= off) inc += u;
            }
            if (idx < NBUK) lexc[idx] = carry + inc - v;
            carry += __shfl(inc, 63, 64);
        }
        if (t == 0) totalLocal = carry;
    }
    __syncthreads();

    for (int i = t; i < NBUK; i += 256) {
        const int c = lcnt[i];
        lgb[i] = c ? atomicAdd(&bucketCnt[i], c) : 0;
        lcnt[i] = 0;
    }
    __syncthreads();

    #pragma unroll
    for (int j = 0; j < 16; ++j) {
        if (bk[j] >= 0) {
            const int r = atomicAdd(&lcnt[bk[j]], 1);
            const int p = lexc[bk[j]] + r;
            stg[p] = pk[j];
            int slot = lgb[bk[j]] + r;
            if (slot >= CAP) slot = CAP - 1;   // statistically impossible
            tgt[p] = bk[j] * CAP + slot;
        }
    }
    __syncthreads();

    const int tot = totalLocal;
    for (int i = t; i < tot; i += 256)
        gBuf[tgt[i]] = stg[i];
}

__global__ __launch_bounds__(64) void k_bbase(
    const int* __restrict__ bucketCnt, int* __restrict__ bucketBase,
    int* __restrict__ row_ptr)
{
    const int t = threadIdx.x;
    int carry = 0;
    for (int c = 0; c < NBUK; c += 64) {
        const int idx = c + t;
        int v = (idx < NBUK) ? bucketCnt[idx] : 0;
        int inc = v;
        #pragma unroll
        for (int off = 1; off < 64; off <<= 1) {
            int u = __shfl_up(inc, off, 64);
            if (t >= off) inc += u;
        }
        if (idx < NBUK) bucketBase[idx] = carry + inc - v;
        carry += __shfl(inc, 63, 64);
    }
    if (t == 0) row_ptr[NN] = NE;
}

__global__ __launch_bounds__(256) void k_csr_local(
    const int* __restrict__ bucketCnt, const int* __restrict__ bucketBase,
    const int* __restrict__ gBuf,
    int* __restrict__ row_ptr, int* __restrict__ ssrc)
{
    __shared__ int stg2[CAP];
    __shared__ int stg3[CAP];
    __shared__ int c2[256];
    __shared__ int sc[256];
    const int t = threadIdx.x;
    const int k = blockIdx.x;
    const int cnt = min(bucketCnt[k], CAP);
    const int gb  = bucketBase[k];

    c2[t] = 0;
    __syncthreads();
    for (int i = t; i < cnt; i += 256) {
        const int pk = gBuf[k * CAP + i];
        stg2[i] = pk;
        atomicAdd(&c2[pk & 255], 1);
    }
    __syncthreads();
    if (t < 64) {
        int carry = 0;
        for (int c = 0; c < 256; c += 64) {
            int v = c2[c + t];
            int inc = v;
            #pragma unroll
            for (int off = 1; off < 64; off <<= 1) {
                int u = __shfl_up(inc, off, 64);
                if (t >= off) inc += u;
            }
            sc[c + t] = carry + inc - v;
            carry += __shfl(inc, 63, 64);
        }
    }
    __syncthreads();
    const int node = (k << 8) + t;
    if (node < NN) row_ptr[node] = gb + sc[t];
    c2[t] = 0;
    __syncthreads();
    for (int i = t; i < cnt; i += 256) {
        const int pk = stg2[i];
        const int dl = pk & 255;
        const int r = atomicAdd(&c2[dl], 1);
        stg3[sc[dl] + r] = pk >> 8;
    }
    __syncthreads();
    for (int i = t; i < cnt; i += 256)
        ssrc[gb + i] = stg3[i];
}

// ---------------- Layer kernels (H=4, D=16, F=64) ----------------

// GEMM z = x@W (fp16 out) + attention coeffs. W column in 64 VGPRs per lane;
// x rows loaded via the SCALAR pipe (wave-uniform address -> s_load), so
// v_fma takes x from SGPR + W from VGPR: zero LDS, no staging, no barrier.
// 64 nodes/block (16/wave), grid = ceil(NN/64) = 1563.
__global__ __launch_bounds__(256) void k_node_prep(
    const float* __restrict__ xin, const float* __restrict__ W,
    const float* __restrict__ al, const float* __restrict__ ar,
    __half* __restrict__ z, float* __restrict__ el, float* __restrict__ er)
{
    const int t = threadIdx.x;
    const int lane = t & 63;
    const int wvU = __builtin_amdgcn_readfirstlane(t >> 6);   // uniform wave id
    const int nodeBase = blockIdx.x * 64 + wvU * 16;

    // W column `lane` into 64 VGPRs (coalesced per k, L2-hot)
    float wc[64];
    #pragma unroll
    for (int k = 0; k < 64; ++k) wc[k] = W[k * 64 + lane];
    const float a_l = al[lane], a_r = ar[lane];

    #pragma unroll 1
    for (int i = 0; i < 16; i += 2) {
        const int nA = nodeBase + i;
        if (nA >= NN) break;                       // uniform branch
        const int nB = nA + 1;
        const bool hasB = (nB < NN);
        // uniform row pointers -> scalar loads
        const float4* __restrict__ xA4 = (const float4*)(xin + (size_t)nA * 64);
        const float4* __restrict__ xB4 = (const float4*)(xin + (size_t)(hasB ? nB : nA) * 64);

        float accA = 0.f, accB = 0.f;
        #pragma unroll
        for (int k4 = 0; k4 < 16; ++k4) {
            const float4 a4 = xA4[k4];
            const float4 b4 = xB4[k4];
            const float w0 = wc[k4 * 4 + 0], w1 = wc[k4 * 4 + 1];
            const float w2 = wc[k4 * 4 + 2], w3 = wc[k4 * 4 + 3];
            accA += a4.x * w0 + a4.y * w1 + a4.z * w2 + a4.w * w3;
            accB += b4.x * w0 + b4.y * w1 + b4.z * w2 + b4.w * w3;
        }

        // epilogue node A
        {
            z[(size_t)nA * 64 + lane] = __float2half(accA);
            float pl = accA * a_l, pr = accA * a_r;
            #pragma unroll
            for (int off = 8; off > 0; off >>= 1) {
                pl += __shfl_xor(pl, off, 16);
                pr += __shfl_xor(pr, off, 16);
            }
            if ((lane & 15) == 0) {
                const int h = lane >> 4;
                el[nA * 4 + h] = pl;
                er[nA * 4 + h] = pr;
            }
        }
        // epilogue node B
        if (hasB) {
            z[(size_t)nB * 64 + lane] = __float2half(accB);
            float pl = accB * a_l, pr = accB * a_r;
            #pragma unroll
            for (int off = 8; off > 0; off >>= 1) {
                pl += __shfl_xor(pl, off, 16);
                pr += __shfl_xor(pr, off, 16);
            }
            if ((lane & 15) == 0) {
                const int h = lane >> 4;
                el[nB * 4 + h] = pl;
                er[nB * 4 + h] = pr;
            }
        }
    }
}

// Fused aggregation: 16 lanes per z-row (half4/lane) -> one wave-load fetches
// 4 edges' rows (8 lines in flight). Exp-dedup: lane l computes exp for
// (edge l>>2, head l&3) per 16-edge chunk. No max pass.
__global__ __launch_bounds__(256) void k_csr_agg(
    const int* __restrict__ row_ptr, const int* __restrict__ ssrc,
    const float* __restrict__ el, const float* __restrict__ er,
    const __half* __restrict__ z, const float* __restrict__ b,
    float* __restrict__ xout,       // [NN][64] or nullptr
    const float* __restrict__ Wo,   // [64] (used when xout==nullptr)
    float* __restrict__ zo)         // [NN]  (used when xout==nullptr)
{
    const int t = threadIdx.x;
    const int wv = t >> 6, l = t & 63;
    const int sg = l >> 4, sl = l & 15;
    const int eh = l & 3;             // head this lane evaluates exp for
    const int hh = sl >> 2;           // head of this lane's feature quad
    const int n = blockIdx.x * 4 + wv;
    const int beg = row_ptr[n], deg = row_ptr[n + 1] - beg;
    const float er_eh = er[n * 4 + eh];

    float4 acc = {0.f, 0.f, 0.f, 0.f};
    float den4 = 0.f;
    for (int base = 0; base < deg; base += 16) {
        const int myE = base + (l >> 2);
        int s = 0; float x = 0.f;
        if (myE < deg) {
            s = ssrc[beg + myE];
            x = __expf(leaky02(el[s * 4 + eh] + er_eh));
        }
        den4 += x;
        const int rem = deg - base;
        const int nk = (min(rem, 16) + 3) >> 2;
        for (int k = 0; k < nk; ++k) {
            const int ec = k * 4 + sg;                       // edge in chunk
            const int   sj = __shfl(s, ec * 4, 64);
            const float xj = __shfl(x, ec * 4 + hh, 64);
            const uint2 raw = *(const uint2*)(z + (size_t)sj * 64 + sl * 4);
            const float2 f01 = __half22float2(*(const __half2*)&raw.x);
            const float2 f23 = __half22float2(*(const __half2*)&raw.y);
            acc.x += xj * f01.x; acc.y += xj * f01.y;
            acc.z += xj * f23.x; acc.w += xj * f23.y;
        }
    }
    #pragma unroll
    for (int off = 16; off < 64; off <<= 1) {
        acc.x += __shfl_xor(acc.x, off, 64);
        acc.y += __shfl_xor(acc.y, off, 64);
        acc.z += __shfl_xor(acc.z, off, 64);
        acc.w += __shfl_xor(acc.w, off, 64);
    }
    #pragma unroll
    for (int off = 4; off < 64; off <<= 1) den4 += __shfl_xor(den4, off, 64);
    const float den = fmaxf(__shfl(den4, hh, 64), 1e-9f);

    const float4 b4 = *(const float4*)(b + sl * 4);
    float4 v;
    v.x = fmaxf(acc.x / den + b4.x, 0.f);
    v.y = fmaxf(acc.y / den + b4.y, 0.f);
    v.z = fmaxf(acc.z / den + b4.z, 0.f);
    v.w = fmaxf(acc.w / den + b4.w, 0.f);

    if (xout) {
        if (l < 16) *(float4*)(xout + (size_t)n * 64 + sl * 4) = v;
    } else {
        const float4 w4 = *(const float4*)(Wo + sl * 4);
        float p = v.x * w4.x + v.y * w4.y + v.z * w4.z + v.w * w4.w;
        #pragma unroll
        for (int off = 1; off < 16; off <<= 1) p += __shfl_xor(p, off, 64);
        if (l == 0) zo[n] = p;
    }
}

// ---------------- Output layer (H=1, D=1), single-pass, 16 lanes/node -------

__global__ __launch_bounds__(256) void k_csr_agg_o(
    const int* __restrict__ row_ptr, const int* __restrict__ ssrc,
    const float* __restrict__ zo, const float* __restrict__ alo,
    const float* __restrict__ aro, const float* __restrict__ bo,
    float* __restrict__ out)
{
    const int t = threadIdx.x, l = t & 15;
    const int n = blockIdx.x * 16 + (t >> 4);
    const float a = alo[0];
    const float zr = aro[0] * zo[n];
    const int beg = row_ptr[n], end = row_ptr[n + 1];

    float den = 0.f, accv = 0.f;
    for (int i = beg + l; i < end; i += 16) {
        const float zs = zo[ssrc[i]];
        const float ex = __expf(leaky02(a * zs + zr));
        den += ex; accv += ex * zs;
    }
    #pragma unroll
    for (int off = 8; off; off >>= 1) {
        den  += __shfl_xor(den, off, 16);
        accv += __shfl_xor(accv, off, 16);
    }
    if (l == 0) out[n] = accv / fmaxf(den, 1e-9f) + bo[0];
}

// ---------------- Launch ----------------

extern "C" void kernel_launch(void* const* d_in, const int* in_sizes, int n_in,
                              void* d_out, int out_size, void* d_ws, size_t ws_size,
                              hipStream_t stream) {
    const float* feat = (const float*)d_in[0];
    const int*   src  = (const int*)d_in[1];
    const int*   dst  = (const int*)d_in[2];
    const float* W0   = (const float*)d_in[3];
    const float* al0  = (const float*)d_in[4];
    const float* ar0  = (const float*)d_in[5];
    const float* b0   = (const float*)d_in[6];
    const float* W1   = (const float*)d_in[7];
    const float* al1  = (const float*)d_in[8];
    const float* ar1  = (const float*)d_in[9];
    const float* b1   = (const float*)d_in[10];
    const float* Wo   = (const float*)d_in[11];
    const float* alo  = (const float*)d_in[12];
    const float* aro  = (const float*)d_in[13];
    const float* bo   = (const float*)d_in[14];
    float* out = (float*)d_out;

    // workspace carve-up (int region padded so z/xA are 16B-aligned)
    int* bucketCnt  = (int*)d_ws;                   // [NBUK] (zeroed)
    int* bucketBase = bucketCnt + NBUK;             // [NBUK]
    int* row_ptr    = bucketBase + NBUK;            // [NN+1]
    int* gBuf       = row_ptr + (NN + 2);           // [NBUK*CAP] (+1 pad int)
    int* ssrc       = gBuf + (size_t)NBUK * CAP;    // [NE]
    __half* z  = (__half*)(ssrc + NE);              // [NN*64] fp16, 16B-aligned
    float* xA  = (float*)(z + (size_t)NN * 64);     // [NN*64]
    float* el  = xA + (size_t)NN * 64;              // [NN*4]
    float* er  = el + (size_t)NN * 4;               // [NN*4]
    float* zo  = er + (size_t)NN * 4;               // [NN]

    const int gPrep = (NN + 63) / 64;    // 1563
    const int gN16  = NN / 16;           // 6250
    const int gAgg  = NN / 4;            // 25000

    // CSR build (LDS radix, 3 kernels)
    hipMemsetAsync(bucketCnt, 0, NBUK * sizeof(int), stream);
    k_bucket   <<<NBUK, 256, 0, stream>>>(src, dst, bucketCnt, gBuf);
    k_bbase    <<<1, 64, 0, stream>>>(bucketCnt, bucketBase, row_ptr);
    k_csr_local<<<NBUK, 256, 0, stream>>>(bucketCnt, bucketBase, gBuf,
                                          row_ptr, ssrc);

    // Layer 0: feat -> xA
    k_node_prep<<<gPrep, 256, 0, stream>>>(feat, W0, al0, ar0, z, el, er);
    k_csr_agg  <<<gAgg, 256, 0, stream>>>(row_ptr, ssrc, el, er, z, b0,
                                          xA, nullptr, nullptr);

    // Layer 1: xA -> zo (output-layer GEMV fused into agg epilogue)
    k_node_prep<<<gPrep, 256, 0, stream>>>(xA, W1, al1, ar1, z, el, er);
    k_csr_agg  <<<gAgg, 256, 0, stream>>>(row_ptr, ssrc, el, er, z, b1,
                                          nullptr, Wo, zo);

    // Output layer
    k_csr_agg_o<<<gN16, 256, 0, stream>>>(row_ptr, ssrc, zo, alo, aro, bo, out);
}

// Round 9
// 280.518 us; speedup vs baseline: 1.2493x; 1.0175x over previous
//
#include <hip/hip_runtime.h>
#include <hip/hip_fp16.h>
#include <math.h>

#define NN 100000
#define NE 1600000
#define NBUK 391        // ceil(NN/256) buckets of 256 dst nodes
#define CAP 4608        // per-bucket region capacity (avg 4096, +8 sigma)
#define EPB 2048        // edges per phase-B block

__device__ __forceinline__ float leaky02(float v) {
    return v > 0.0f ? v : 0.2f * v;
}

// ---------------- CSR build via LDS radix (no device-random atomics) --------

// Phase B: bucket edges by dst>>8, 2048 edges/block, 782 blocks.
__global__ __launch_bounds__(256) void k_bucket(
    const int* __restrict__ src, const int* __restrict__ dst,
    int* __restrict__ bucketCnt, int* __restrict__ gBuf)
{
    __shared__ int stg[EPB];
    __shared__ int tgt[EPB];
    __shared__ int lcnt[NBUK];
    __shared__ int lexc[NBUK];
    __shared__ int lgb[NBUK];
    __shared__ int totalLocal;
    const int t = threadIdx.x;
    const int e0 = blockIdx.x * EPB;

    for (int i = t; i < NBUK; i += 256) lcnt[i] = 0;
    __syncthreads();

    int bk[8], pk[8];
    #pragma unroll
    for (int j = 0; j < 8; ++j) {
        const int e = e0 + j * 256 + t;
        if (e < NE) {
            const int d = dst[e];
            bk[j] = d >> 8;
            pk[j] = (src[e] << 8) | (d & 255);
            atomicAdd(&lcnt[bk[j]], 1);
        } else bk[j] = -1;
    }
    __syncthreads();

    if (t < 64) {
        int carry = 0;
        for (int c = 0; c < NBUK; c += 64) {
            const int idx = c + t;
            int v = (idx < NBUK) ? lcnt[idx] : 0;
            int inc = v;
            #pragma unroll
            for (int off = 1; off < 64; off <<= 1) {
                int u = __shfl_up(inc, off, 64);
                if (t >= off) inc += u;
            }
            if (idx < NBUK) lexc[idx] = carry + inc - v;
            carry += __shfl(inc, 63, 64);
        }
        if (t == 0) totalLocal = carry;
    }
    __syncthreads();

    for (int i = t; i < NBUK; i += 256) {
        const int c = lcnt[i];
        lgb[i] = c ? atomicAdd(&bucketCnt[i], c) : 0;
        lcnt[i] = 0;
    }
    __syncthreads();

    #pragma unroll
    for (int j = 0; j < 8; ++j) {
        if (bk[j] >= 0) {
            const int r = atomicAdd(&lcnt[bk[j]], 1);
            const int p = lexc[bk[j]] + r;
            stg[p] = pk[j];
            int slot = lgb[bk[j]] + r;
            if (slot >= CAP) slot = CAP - 1;   // statistically impossible
            tgt[p] = bk[j] * CAP + slot;
        }
    }
    __syncthreads();

    const int tot = totalLocal;
    for (int i = t; i < tot; i += 256)
        gBuf[tgt[i]] = stg[i];
}

// Phase C: per bucket, compute own global base (prefix over bucketCnt),
// counting-sort by dst&255 in LDS, emit row_ptr + ssrc (streaming writes).
__global__ __launch_bounds__(256) void k_csr_local(
    const int* __restrict__ bucketCnt, const int* __restrict__ gBuf,
    int* __restrict__ row_ptr, int* __restrict__ ssrc)
{
    __shared__ int stg2[CAP];
    __shared__ int stg3[CAP];
    __shared__ int c2[256];
    __shared__ int sc[256];
    __shared__ int red[256];
    const int t = threadIdx.x;
    const int k = blockIdx.x;
    const int cnt = min(bucketCnt[k], CAP);

    // own prefix sum of bucketCnt[0..k)
    int part = 0;
    for (int j = t; j < k; j += 256) part += bucketCnt[j];
    red[t] = part;
    __syncthreads();
    for (int s2 = 128; s2; s2 >>= 1) {
        if (t < s2) red[t] += red[t + s2];
        __syncthreads();
    }
    const int gb = red[0];

    c2[t] = 0;
    __syncthreads();
    for (int i = t; i < cnt; i += 256) {
        const int pk = gBuf[k * CAP + i];
        stg2[i] = pk;
        atomicAdd(&c2[pk & 255], 1);
    }
    __syncthreads();
    if (t < 64) {
        int carry = 0;
        for (int c = 0; c < 256; c += 64) {
            int v = c2[c + t];
            int inc = v;
            #pragma unroll
            for (int off = 1; off < 64; off <<= 1) {
                int u = __shfl_up(inc, off, 64);
                if (t >= off) inc += u;
            }
            sc[c + t] = carry + inc - v;
            carry += __shfl(inc, 63, 64);
        }
    }
    __syncthreads();
    const int node = (k << 8) + t;
    if (node < NN) row_ptr[node] = gb + sc[t];
    if (k == NBUK - 1 && t == 0) row_ptr[NN] = NE;
    c2[t] = 0;
    __syncthreads();
    for (int i = t; i < cnt; i += 256) {
        const int pk = stg2[i];
        const int dl = pk & 255;
        const int r = atomicAdd(&c2[dl], 1);
        stg3[sc[dl] + r] = pk >> 8;
    }
    __syncthreads();
    for (int i = t; i < cnt; i += 256)
        ssrc[gb + i] = stg3[i];
}

// ---------------- Layer kernels (H=4, D=16, F=64) ----------------

// GEMM z = x@W (fp16 out) + attention coeffs. W column in 64 VGPRs per lane;
// x rows loaded via the SCALAR pipe (wave-uniform address -> s_load).
__global__ __launch_bounds__(256) void k_node_prep(
    const float* __restrict__ xin, const float* __restrict__ W,
    const float* __restrict__ al, const float* __restrict__ ar,
    __half* __restrict__ z, float* __restrict__ el, float* __restrict__ er)
{
    const int t = threadIdx.x;
    const int lane = t & 63;
    const int wvU = __builtin_amdgcn_readfirstlane(t >> 6);   // uniform wave id
    const int nodeBase = blockIdx.x * 64 + wvU * 16;

    float wc[64];
    #pragma unroll
    for (int k = 0; k < 64; ++k) wc[k] = W[k * 64 + lane];
    const float a_l = al[lane], a_r = ar[lane];

    #pragma unroll 1
    for (int i = 0; i < 16; i += 2) {
        const int nA = nodeBase + i;
        if (nA >= NN) break;                       // uniform branch
        const int nB = nA + 1;
        const bool hasB = (nB < NN);
        const float4* __restrict__ xA4 = (const float4*)(xin + (size_t)nA * 64);
        const float4* __restrict__ xB4 = (const float4*)(xin + (size_t)(hasB ? nB : nA) * 64);

        float accA = 0.f, accB = 0.f;
        #pragma unroll
        for (int k4 = 0; k4 < 16; ++k4) {
            const float4 a4 = xA4[k4];
            const float4 b4 = xB4[k4];
            const float w0 = wc[k4 * 4 + 0], w1 = wc[k4 * 4 + 1];
            const float w2 = wc[k4 * 4 + 2], w3 = wc[k4 * 4 + 3];
            accA += a4.x * w0 + a4.y * w1 + a4.z * w2 + a4.w * w3;
            accB += b4.x * w0 + b4.y * w1 + b4.z * w2 + b4.w * w3;
        }

        {
            z[(size_t)nA * 64 + lane] = __float2half(accA);
            float pl = accA * a_l, pr = accA * a_r;
            #pragma unroll
            for (int off = 8; off > 0; off >>= 1) {
                pl += __shfl_xor(pl, off, 16);
                pr += __shfl_xor(pr, off, 16);
            }
            if ((lane & 15) == 0) {
                const int h = lane >> 4;
                el[nA * 4 + h] = pl;
                er[nA * 4 + h] = pr;
            }
        }
        if (hasB) {
            z[(size_t)nB * 64 + lane] = __float2half(accB);
            float pl = accB * a_l, pr = accB * a_r;
            #pragma unroll
            for (int off = 8; off > 0; off >>= 1) {
                pl += __shfl_xor(pl, off, 16);
                pr += __shfl_xor(pr, off, 16);
            }
            if ((lane & 15) == 0) {
                const int h = lane >> 4;
                el[nB * 4 + h] = pl;
                er[nB * 4 + h] = pr;
            }
        }
    }
}

// Fused aggregation, direct-subgroup form: 16-lane subgroup sg owns edges
// beg+sg, beg+sg+4, ... (ssrc read = same-address broadcast; el gather = one
// 16B line per edge). Unroll x2 -> 8 z-rows in flight per wave. No shfl in
// the inner loop; er preloaded. No max pass (exp(e) fp32-safe).
__global__ __launch_bounds__(256) void k_csr_agg(
    const int* __restrict__ row_ptr, const int* __restrict__ ssrc,
    const float* __restrict__ el, const float* __restrict__ er,
    const __half* __restrict__ z, const float* __restrict__ b,
    float* __restrict__ xout,       // [NN][64] or nullptr
    const float* __restrict__ Wo,   // [64] (used when xout==nullptr)
    float* __restrict__ zo)         // [NN]  (used when xout==nullptr)
{
    const int t = threadIdx.x;
    const int wv = t >> 6, l = t & 63;
    const int sg = l >> 4, sl = l & 15;
    const int hh = sl >> 2;           // head of this lane's feature quad
    const int n = blockIdx.x * 4 + wv;
    const int beg = row_ptr[n], end = row_ptr[n + 1];
    const float er_hh = er[n * 4 + hh];

    float4 acc = {0.f, 0.f, 0.f, 0.f};
    float den = 0.f;
    int i = beg + sg;
    for (; i + 4 < end; i += 8) {
        const int s0 = ssrc[i], s1 = ssrc[i + 4];
        const float x0 = __expf(leaky02(el[s0 * 4 + hh] + er_hh));
        const float x1 = __expf(leaky02(el[s1 * 4 + hh] + er_hh));
        const uint2 r0 = *(const uint2*)(z + (size_t)s0 * 64 + sl * 4);
        const uint2 r1 = *(const uint2*)(z + (size_t)s1 * 64 + sl * 4);
        den += x0 + x1;
        const float2 p0 = __half22float2(*(const __half2*)&r0.x);
        const float2 q0 = __half22float2(*(const __half2*)&r0.y);
        const float2 p1 = __half22float2(*(const __half2*)&r1.x);
        const float2 q1 = __half22float2(*(const __half2*)&r1.y);
        acc.x += x0 * p0.x + x1 * p1.x;
        acc.y += x0 * p0.y + x1 * p1.y;
        acc.z += x0 * q0.x + x1 * q1.x;
        acc.w += x0 * q0.y + x1 * q1.y;
    }
    if (i < end) {
        const int s0 = ssrc[i];
        const float x0 = __expf(leaky02(el[s0 * 4 + hh] + er_hh));
        const uint2 r0 = *(const uint2*)(z + (size_t)s0 * 64 + sl * 4);
        den += x0;
        const float2 p0 = __half22float2(*(const __half2*)&r0.x);
        const float2 q0 = __half22float2(*(const __half2*)&r0.y);
        acc.x += x0 * p0.x; acc.y += x0 * p0.y;
        acc.z += x0 * q0.x; acc.w += x0 * q0.y;
    }

    // combine the 4 subgroups (each lane ends with full sums for quad sl,
    // den for head hh = sl>>2)
    #pragma unroll
    for (int off = 16; off < 64; off <<= 1) {
        acc.x += __shfl_xor(acc.x, off, 64);
        acc.y += __shfl_xor(acc.y, off, 64);
        acc.z += __shfl_xor(acc.z, off, 64);
        acc.w += __shfl_xor(acc.w, off, 64);
        den   += __shfl_xor(den,   off, 64);
    }
    const float dinv = 1.0f / fmaxf(den, 1e-9f);

    const float4 b4 = *(const float4*)(b + sl * 4);
    float4 v;
    v.x = fmaxf(acc.x * dinv + b4.x, 0.f);
    v.y = fmaxf(acc.y * dinv + b4.y, 0.f);
    v.z = fmaxf(acc.z * dinv + b4.z, 0.f);
    v.w = fmaxf(acc.w * dinv + b4.w, 0.f);

    if (xout) {
        if (l < 16) *(float4*)(xout + (size_t)n * 64 + sl * 4) = v;
    } else {
        const float4 w4 = *(const float4*)(Wo + sl * 4);
        float p = v.x * w4.x + v.y * w4.y + v.z * w4.z + v.w * w4.w;
        #pragma unroll
        for (int off = 1; off < 16; off <<= 1) p += __shfl_xor(p, off, 64);
        if (l == 0) zo[n] = p;
    }
}

// ---------------- Output layer (H=1, D=1), single-pass, 16 lanes/node -------

__global__ __launch_bounds__(256) void k_csr_agg_o(
    const int* __restrict__ row_ptr, const int* __restrict__ ssrc,
    const float* __restrict__ zo, const float* __restrict__ alo,
    const float* __restrict__ aro, const float* __restrict__ bo,
    float* __restrict__ out)
{
    const int t = threadIdx.x, l = t & 15;
    const int n = blockIdx.x * 16 + (t >> 4);
    const float a = alo[0];
    const float zr = aro[0] * zo[n];
    const int beg = row_ptr[n], end = row_ptr[n + 1];

    float den = 0.f, accv = 0.f;
    for (int i = beg + l; i < end; i += 16) {
        const float zs = zo[ssrc[i]];
        const float ex = __expf(leaky02(a * zs + zr));
        den += ex; accv += ex * zs;
    }
    #pragma unroll
    for (int off = 8; off; off >>= 1) {
        den  += __shfl_xor(den, off, 16);
        accv += __shfl_xor(accv, off, 16);
    }
    if (l == 0) out[n] = accv / fmaxf(den, 1e-9f) + bo[0];
}

// ---------------- Launch ----------------

extern "C" void kernel_launch(void* const* d_in, const int* in_sizes, int n_in,
                              void* d_out, int out_size, void* d_ws, size_t ws_size,
                              hipStream_t stream) {
    const float* feat = (const float*)d_in[0];
    const int*   src  = (const int*)d_in[1];
    const int*   dst  = (const int*)d_in[2];
    const float* W0   = (const float*)d_in[3];
    const float* al0  = (const float*)d_in[4];
    const float* ar0  = (const float*)d_in[5];
    const float* b0   = (const float*)d_in[6];
    const float* W1   = (const float*)d_in[7];
    const float* al1  = (const float*)d_in[8];
    const float* ar1  = (const float*)d_in[9];
    const float* b1   = (const float*)d_in[10];
    const float* Wo   = (const float*)d_in[11];
    const float* alo  = (const float*)d_in[12];
    const float* aro  = (const float*)d_in[13];
    const float* bo   = (const float*)d_in[14];
    float* out = (float*)d_out;

    // workspace carve-up (int region padded so z/xA are 16B-aligned)
    int* bucketCnt  = (int*)d_ws;                   // [NBUK] (zeroed)
    int* row_ptr    = bucketCnt + NBUK;             // [NN+1]
    int* gBuf       = row_ptr + (NN + 2);           // [NBUK*CAP] (+1 pad int)
    int* ssrc       = gBuf + (size_t)NBUK * CAP;    // [NE]
    __half* z  = (__half*)(ssrc + NE);              // [NN*64] fp16, 16B-aligned
    float* xA  = (float*)(z + (size_t)NN * 64);     // [NN*64]
    float* el  = xA + (size_t)NN * 64;              // [NN*4]
    float* er  = el + (size_t)NN * 4;               // [NN*4]
    float* zo  = er + (size_t)NN * 4;               // [NN]

    const int gBkt  = (NE + EPB - 1) / EPB;  // 782
    const int gPrep = (NN + 63) / 64;        // 1563
    const int gN16  = NN / 16;               // 6250
    const int gAgg  = NN / 4;                // 25000

    // CSR build (LDS radix, 2 kernels + memset)
    hipMemsetAsync(bucketCnt, 0, NBUK * sizeof(int), stream);
    k_bucket   <<<gBkt, 256, 0, stream>>>(src, dst, bucketCnt, gBuf);
    k_csr_local<<<NBUK, 256, 0, stream>>>(bucketCnt, gBuf, row_ptr, ssrc);

    // Layer 0: feat -> xA
    k_node_prep<<<gPrep, 256, 0, stream>>>(feat, W0, al0, ar0, z, el, er);
    k_csr_agg  <<<gAgg, 256, 0, stream>>>(row_ptr, ssrc, el, er, z, b0,
                                          xA, nullptr, nullptr);

    // Layer 1: xA -> zo (output-layer GEMV fused into agg epilogue)
    k_node_prep<<<gPrep, 256, 0, stream>>>(xA, W1, al1, ar1, z, el, er);
    k_csr_agg  <<<gAgg, 256, 0, stream>>>(row_ptr, ssrc, el, er, z, b1,
                                          nullptr, Wo, zo);

    // Output layer
    k_csr_agg_o<<<gN16, 256, 0, stream>>>(row_ptr, ssrc, zo, alo, aro, bo, out);
}